// Round 8
// baseline (268.383 us; speedup 1.0000x reference)
//
#include <hip/hip_runtime.h>
#include <hip/hip_bf16.h>

// GCN 2-layer, fully fused: 6 kernel launches.
//   p1  : bucket histogram + edge_index copy-out + W1/W2 transpose->bf16
//   p2a : scan of per-partition bucket counts
//   p3  : partition edges into bucket-contiguous ebuf
//   p4  : per-bucket counting sort -> csr (ushort), rowptr, dis, Xhs=bf16(dis*X)
//   fused<KP,true>  : gather Xhs->LDS, MFMA @W1, epilogue g2h=bf16(relu(d*a+b1)*d)
//   fused<HID,false>: gather g2h->LDS, MFMA @W2, epilogue out=relu(d*a+b2)
// All row operands bf16 (fp32 accumulation). Requires N < 65536.

#define HID 128
#define KIN 89
#define KP 96     // padded input dim
#define BSH 8     // bucket = 256 nodes
#define BNODES 256
#define MAXBUCK 256
#define NPB 128       // partition blocks
#define P4CAP 6144    // staging capacity per bucket (mean ~4081)

typedef __attribute__((ext_vector_type(8))) short bf16x8;
typedef __attribute__((ext_vector_type(4))) float f32x4;

static __device__ inline float2 unpack_bf16(unsigned v) {
    union { unsigned u; float f; } lo, hi;
    lo.u = v << 16;
    hi.u = v & 0xFFFF0000u;
    return make_float2(lo.f, hi.f);
}

static __device__ inline unsigned pack_bf16(float a, float b) {
    __hip_bfloat162 h = __float22bfloat162_rn(make_float2(a, b));
    return *reinterpret_cast<unsigned*>(&h);
}

static __device__ inline unsigned short f2bf(float v) {
    __hip_bfloat16 h = __float2bfloat16(v);
    return *reinterpret_cast<unsigned short*>(&h);
}

// ---- p1: histogram + edge copy + weight transposes ----
__global__ __launch_bounds__(256) void p1_kernel(
    const int* __restrict__ ei, float* __restrict__ outE,
    int* __restrict__ histG,
    const float* __restrict__ W1, unsigned short* __restrict__ W1t,
    const float* __restrict__ W2, unsigned short* __restrict__ W2t,
    int E, int nbuck)
{
    __shared__ int h[MAXBUCK];
    const int tid = threadIdx.x, blk = blockIdx.x;
    const int* src = ei;
    const int* dst = ei + E;
    if (tid < nbuck) h[tid] = 0;

    // weight transposes spread over the grid's first 28672 threads
    int tg = blk * 256 + tid;
    if (tg < HID * KP) {
        int n = tg / KP, k = tg % KP;
        W1t[tg] = f2bf(k < KIN ? W1[(size_t)k * HID + n] : 0.0f);
    } else {
        int t2 = tg - HID * KP;
        if (t2 < HID * HID) {
            int n = t2 / HID, k = t2 % HID;
            W2t[t2] = f2bf(W2[(size_t)k * HID + n]);
        }
    }
    __syncthreads();

    const int chunk = (E + NPB - 1) / NPB;
    const int beg = blk * chunk, end = min(beg + chunk, E);
    for (int i = beg + tid; i < end; i += 256) {
        int d = dst[i];
        atomicAdd(&h[d >> BSH], 1);
        outE[i] = (float)src[i];
        outE[E + i] = (float)d;
    }
    __syncthreads();
    if (tid < nbuck) histG[tid * NPB + blk] = h[tid];
}

// ---- p2a: per-bucket exclusive scan of its NPB counts + totals ----
__global__ __launch_bounds__(NPB) void p2a_kernel(
    int* __restrict__ histG, int* __restrict__ totals)
{
    __shared__ int wsum[NPB / 64];
    const int b = blockIdx.x, tid = threadIdx.x, lane = tid & 63, wid = tid >> 6;
    int c = histG[b * NPB + tid];
    int s = c;
#pragma unroll
    for (int off = 1; off < 64; off <<= 1) {
        int t = __shfl_up(s, off, 64);
        if (lane >= off) s += t;
    }
    if (lane == 63) wsum[wid] = s;
    __syncthreads();
    if (tid == 0) {
        int a = 0;
#pragma unroll
        for (int w = 0; w < NPB / 64; ++w) { int t = wsum[w]; wsum[w] = a; a += t; }
    }
    __syncthreads();
    int excl = wsum[wid] + s - c;
    histG[b * NPB + tid] = excl;
    if (tid == NPB - 1) totals[b] = excl + c;
}

// In-block exclusive scan of totals[0..nbuck) -> sexcl[tid] (256 threads).
static __device__ inline void scan_totals(const int* __restrict__ totals,
                                          int* __restrict__ sexcl,
                                          int* __restrict__ wsum,
                                          int nbuck, int tid)
{
    const int lane = tid & 63, wid = tid >> 6;
    int v = (tid < nbuck) ? totals[tid] : 0;
    int s = v;
#pragma unroll
    for (int off = 1; off < 64; off <<= 1) {
        int t = __shfl_up(s, off, 64);
        if (lane >= off) s += t;
    }
    if (lane == 63) wsum[wid] = s;
    __syncthreads();
    if (tid == 0) {
        int a = 0;
#pragma unroll
        for (int w = 0; w < 4; ++w) { int t = wsum[w]; wsum[w] = a; a += t; }
    }
    __syncthreads();
    sexcl[tid] = wsum[wid] + s - v;
}

// ---- p3: partition edges into bucket-contiguous ebuf ----
__global__ __launch_bounds__(256) void p3_part_kernel(
    const int* __restrict__ ei, const int* __restrict__ histG,
    const int* __restrict__ totals, unsigned* __restrict__ ebuf,
    int E, int nbuck)
{
    __shared__ int cur[MAXBUCK];
    __shared__ int wsum[4];
    const int tid = threadIdx.x, blk = blockIdx.x;
    const int* src = ei;
    const int* dst = ei + E;
    scan_totals(totals, cur, wsum, nbuck, tid);   // cur[tid] = bucket base
    __syncthreads();
    if (tid < nbuck) cur[tid] += histG[tid * NPB + blk];
    const int chunk = (E + NPB - 1) / NPB;
    const int beg = blk * chunk, end = min(beg + chunk, E);
    __syncthreads();
    for (int i = beg + tid; i < end; i += 256) {
        int d = dst[i];
        int b = d >> BSH;
        int pos = atomicAdd(&cur[b], 1);
        ebuf[pos] = ((unsigned)(d & (BNODES - 1)) << 16) | (unsigned)src[i];
    }
}

// ---- p4: per-bucket sort -> csr, rowptr, dis, Xhs ----
__global__ __launch_bounds__(256) void p4_sort_kernel(
    const unsigned* __restrict__ ebuf, const int* __restrict__ totals,
    unsigned short* __restrict__ csr, int* __restrict__ rowptr,
    float* __restrict__ dis, const float* __restrict__ X,
    unsigned* __restrict__ Xhs, int N, int E, int nbuck)
{
    __shared__ int counts[BNODES];
    __shared__ int cursor[BNODES];
    __shared__ int sbase[MAXBUCK];
    __shared__ int wsum[4];
    __shared__ float sdis[BNODES];
    __shared__ unsigned short staging[P4CAP];
    const int b = blockIdx.x, tid = threadIdx.x, lane = tid & 63, wid = tid >> 6;

    scan_totals(totals, sbase, wsum, nbuck, tid);
    __syncthreads();
    const int gbase = sbase[b];
    const int cnt = totals[b];

    counts[tid] = 0;
    __syncthreads();
    for (int i = tid; i < cnt; i += 256)
        atomicAdd(&counts[ebuf[gbase + i] >> 16], 1);
    __syncthreads();

    int c = counts[tid];
    int s = c;
#pragma unroll
    for (int off = 1; off < 64; off <<= 1) {
        int t = __shfl_up(s, off, 64);
        if (lane >= off) s += t;
    }
    if (lane == 63) wsum[wid] = s;
    __syncthreads();
    if (tid == 0) {
        int a = 0;
#pragma unroll
        for (int w = 0; w < 4; ++w) { int t = wsum[w]; wsum[w] = a; a += t; }
    }
    __syncthreads();
    int excl = wsum[wid] + s - c;
    cursor[tid] = excl;
    float dd = rsqrtf(1.0f + (float)c);
    sdis[tid] = dd;
    int node = b * BNODES + tid;
    if (node < N) {
        rowptr[node] = gbase + excl;
        dis[node] = dd;
    }
    if (b == 0 && tid == 0) rowptr[N] = E;
    __syncthreads();

    if (cnt <= P4CAP) {
        for (int i = tid; i < cnt; i += 256) {
            unsigned v = ebuf[gbase + i];
            int pos = atomicAdd(&cursor[v >> 16], 1);
            staging[pos] = (unsigned short)(v & 0xFFFFu);
        }
        __syncthreads();
        for (int i = tid; i < cnt; i += 256)
            csr[gbase + i] = staging[i];
    } else {
        for (int i = tid; i < cnt; i += 256) {
            unsigned v = ebuf[gbase + i];
            int pos = atomicAdd(&cursor[v >> 16], 1);
            csr[gbase + pos] = (unsigned short)(v & 0xFFFFu);
        }
    }

    // Xhs = bf16(dis * X) for this bucket's nodes (coalesced)
    const int nodeBase = b * BNODES;
    for (int idx = tid; idx < BNODES * (KP / 2); idx += 256) {
        int nl = idx / (KP / 2), cc = idx % (KP / 2);
        int nd = nodeBase + nl;
        if (nd < N) {
            const float* xr = X + (size_t)nd * KIN;
            float d = sdis[nl];
            float a = (2 * cc     < KIN) ? d * xr[2 * cc]     : 0.0f;
            float bb = (2 * cc + 1 < KIN) ? d * xr[2 * cc + 1] : 0.0f;
            Xhs[(size_t)nd * (KP / 2) + cc] = pack_bf16(a, bb);
        }
    }
}

// ---- fused layer: CSR gather -> LDS -> MFMA GEMM -> epilogue ----
// Block = 64 nodes, 4 waves. Phase 1: wave w gathers nodes w*16..+15 into
// LDS (bf16 pairs, padded stride -> conflict-optimal ds_read_b128).
// Phase 2: 8x 16x16x32 MFMA per wave, node-frag from LDS, Wt from L2.
// rows are pre-scaled by dis[src]; dis[node] applied in epilogue:
//   LAYER1: g2h = bf16(relu(d*a + b)*d)   LAYER2: out = relu(d*a + b) fp32
template<int KPA, bool LAYER1>
__global__ __launch_bounds__(256) void fused_layer_kernel(
    const unsigned* __restrict__ rows, const int* __restrict__ rowptr,
    const unsigned short* __restrict__ csr, const float* __restrict__ dis,
    const unsigned short* __restrict__ Wt, const float* __restrict__ bias,
    void* __restrict__ outp, int N)
{
    constexpr int PAIRS = KPA / 2;
    constexpr int S = PAIRS + 4;          // word stride (bank-optimal)
    __shared__ unsigned lds[64 * S];
    const int wave = threadIdx.x >> 6;
    const int lane = threadIdx.x & 63;
    const int node0 = blockIdx.x * 64;
    const bool act = lane < PAIRS;

    // phase 1: gather
    for (int i = 0; i < 16; ++i) {
        const int nl = wave * 16 + i;
        const int node = node0 + nl;
        float a0 = 0.0f, a1 = 0.0f;
        if (node < N) {
            if (act) {
                float2 v = unpack_bf16(rows[(size_t)node * PAIRS + lane]);  // self
                a0 = v.x; a1 = v.y;
            }
            const int beg = rowptr[node], end = rowptr[node + 1];
            for (int cb = beg; cb < end; cb += 64) {
                const int cnt = min(64, end - cb);
                int idxv = csr[cb + (lane < cnt ? lane : cnt - 1)];
                int j = 0;
                for (; j + 4 <= cnt; j += 4) {
                    int s0 = __shfl(idxv, j);
                    int s1 = __shfl(idxv, j + 1);
                    int s2 = __shfl(idxv, j + 2);
                    int s3 = __shfl(idxv, j + 3);
                    if (act) {
                        float2 v0 = unpack_bf16(rows[(size_t)s0 * PAIRS + lane]);
                        float2 v1 = unpack_bf16(rows[(size_t)s1 * PAIRS + lane]);
                        float2 v2 = unpack_bf16(rows[(size_t)s2 * PAIRS + lane]);
                        float2 v3 = unpack_bf16(rows[(size_t)s3 * PAIRS + lane]);
                        a0 += v0.x + v1.x + v2.x + v3.x;
                        a1 += v0.y + v1.y + v2.y + v3.y;
                    }
                }
                for (; j < cnt; ++j) {
                    int sx = __shfl(idxv, j);
                    if (act) {
                        float2 v = unpack_bf16(rows[(size_t)sx * PAIRS + lane]);
                        a0 += v.x; a1 += v.y;
                    }
                }
            }
        }
        if (act) lds[nl * S + lane] = pack_bf16(a0, a1);
    }
    __syncthreads();

    // phase 2: MFMA
    const int m    = lane & 15;
    const int quad = lane >> 4;
    const int nl   = wave * 16 + m;
    const int node = node0 + nl;

    f32x4 acc[8];
#pragma unroll
    for (int t = 0; t < 8; ++t) acc[t] = (f32x4){0.0f, 0.0f, 0.0f, 0.0f};

#pragma unroll
    for (int c = 0; c < KPA / 32; ++c) {
        bf16x8 nv = *(const bf16x8*)(lds + nl * S + c * 16 + quad * 4);
        const int k0 = c * 32 + quad * 8;
#pragma unroll
        for (int t = 0; t < 8; ++t) {
            bf16x8 wv = *(const bf16x8*)(Wt + (size_t)(t * 16 + m) * KPA + k0);
            acc[t] = __builtin_amdgcn_mfma_f32_16x16x32_bf16(wv, nv, acc[t], 0, 0, 0);
        }
    }

    if (node < N) {
        const float dv = dis[node];
#pragma unroll
        for (int t = 0; t < 8; ++t) {
            const int col0 = t * 16 + quad * 4;
            float4 bb = *(const float4*)&bias[col0];
            float r0 = fmaxf(fmaf(dv, acc[t][0], bb.x), 0.0f);
            float r1 = fmaxf(fmaf(dv, acc[t][1], bb.y), 0.0f);
            float r2 = fmaxf(fmaf(dv, acc[t][2], bb.z), 0.0f);
            float r3 = fmaxf(fmaf(dv, acc[t][3], bb.w), 0.0f);
            if (LAYER1) {
                uint2 u;
                u.x = pack_bf16(r0 * dv, r1 * dv);
                u.y = pack_bf16(r2 * dv, r3 * dv);
                *(uint2*)((unsigned short*)outp + (size_t)node * HID + col0) = u;
            } else {
                float4 r = make_float4(r0, r1, r2, r3);
                *(float4*)((float*)outp + (size_t)node * HID + col0) = r;
            }
        }
    }
}

// ---------------- launch ----------------

static inline char* wsal(char*& p, size_t n) {
    uintptr_t q = ((uintptr_t)p + 255) & ~(uintptr_t)255;
    char* r = (char*)q;
    p = r + n;
    return r;
}

extern "C" void kernel_launch(void* const* d_in, const int* in_sizes, int n_in,
                              void* d_out, int out_size, void* d_ws, size_t ws_size,
                              hipStream_t stream) {
    const float* x  = (const float*)d_in[0];
    const int*   ei = (const int*)d_in[1];
    const float* W1 = (const float*)d_in[2];
    const float* b1 = (const float*)d_in[3];
    const float* W2 = (const float*)d_in[4];
    const float* b2 = (const float*)d_in[5];

    const int N = in_sizes[0] / KIN;  // 50000  (< 65536 required)
    const int E = in_sizes[1] / 2;    // 800000
    const int nbuck = (N + BNODES - 1) >> BSH;   // 196 (<= MAXBUCK)

    float* out  = (float*)d_out;
    float* outH = out;                      // [N,128] final fp32 output
    float* outE = out + (size_t)N * HID;    // [2,E] edge_index as float

    char* ws = (char*)d_ws;
    int*            histG  = (int*)wsal(ws, (size_t)MAXBUCK * NPB * 4);
    int*            totals = (int*)wsal(ws, MAXBUCK * 4);
    int*            rowptr = (int*)wsal(ws, (size_t)(N + 1) * 4);
    float*          dis    = (float*)wsal(ws, (size_t)N * 4);
    unsigned*       ebuf   = (unsigned*)wsal(ws, (size_t)E * 4);
    unsigned short* csr    = (unsigned short*)wsal(ws, (size_t)E * 2);
    unsigned*       Xhs    = (unsigned*)wsal(ws, (size_t)N * (KP / 2) * 4);
    unsigned short* g2h    = (unsigned short*)wsal(ws, (size_t)N * HID * 2);
    unsigned short* W1t    = (unsigned short*)wsal(ws, (size_t)HID * KP * 2);
    unsigned short* W2t    = (unsigned short*)wsal(ws, (size_t)HID * HID * 2);

    p1_kernel<<<NPB, 256, 0, stream>>>(ei, outE, histG, W1, W1t, W2, W2t, E, nbuck);
    p2a_kernel<<<nbuck, NPB, 0, stream>>>(histG, totals);
    p3_part_kernel<<<NPB, 256, 0, stream>>>(ei, histG, totals, ebuf, E, nbuck);
    p4_sort_kernel<<<nbuck, 256, 0, stream>>>(ebuf, totals, csr, rowptr, dis,
                                              x, Xhs, N, E, nbuck);

    const int ngm = (N + 63) / 64;
    fused_layer_kernel<KP, true><<<ngm, 256, 0, stream>>>(
        Xhs, rowptr, csr, dis, W1t, b1, g2h, N);
    fused_layer_kernel<HID, false><<<ngm, 256, 0, stream>>>(
        (const unsigned*)g2h, rowptr, csr, dis, W2t, b2, outH, N);
}

// Round 9
// 251.317 us; speedup vs baseline: 1.0679x; 1.0679x over previous
//
#include <hip/hip_runtime.h>
#include <hip/hip_bf16.h>

// GCN 2-layer, 8 launches. R7 structure (independent gather waves for MLP)
// + R8's fused prep and pre-scaled rows.
//   p1  : bucket histogram + edge_index copy-out + W1/W2 transpose->bf16
//   p2a : scan of per-partition bucket counts
//   p3  : partition edges into bucket-contiguous ebuf
//   p4  : per-bucket counting sort -> csr(ushort), rowptr, dis, Xhs=bf16(dis*X)
//   gather_x : agg1h = bf16( Xhs_i + sum_s Xhs_s )          (raw sum)
//   gemm1    : g2h   = bf16( relu(d*(agg1h@W1t) + b1) * d )  (MFMA, no LDS)
//   gather_h : agg2h = bf16( g2h_i + sum_s g2h_s )          (raw sum)
//   gemm2    : out   = relu( d*(agg2h@W2t) + b2 )            fp32
// All row operands bf16 (fp32 accumulation). Requires N < 65536.

#define HID 128
#define KIN 89
#define KP 96     // padded input dim
#define BSH 8     // bucket = 256 nodes
#define BNODES 256
#define MAXBUCK 256
#define NPB 128       // partition blocks
#define P4CAP 6144    // staging capacity per bucket (mean ~4081)

typedef __attribute__((ext_vector_type(8))) short bf16x8;
typedef __attribute__((ext_vector_type(4))) float f32x4;

static __device__ inline float2 unpack_bf16(unsigned v) {
    union { unsigned u; float f; } lo, hi;
    lo.u = v << 16;
    hi.u = v & 0xFFFF0000u;
    return make_float2(lo.f, hi.f);
}

static __device__ inline unsigned pack_bf16(float a, float b) {
    __hip_bfloat162 h = __float22bfloat162_rn(make_float2(a, b));
    return *reinterpret_cast<unsigned*>(&h);
}

static __device__ inline unsigned short f2bf(float v) {
    __hip_bfloat16 h = __float2bfloat16(v);
    return *reinterpret_cast<unsigned short*>(&h);
}

// ---- p1: histogram + edge copy + weight transposes ----
__global__ __launch_bounds__(256) void p1_kernel(
    const int* __restrict__ ei, float* __restrict__ outE,
    int* __restrict__ histG,
    const float* __restrict__ W1, unsigned short* __restrict__ W1t,
    const float* __restrict__ W2, unsigned short* __restrict__ W2t,
    int E, int nbuck)
{
    __shared__ int h[MAXBUCK];
    const int tid = threadIdx.x, blk = blockIdx.x;
    const int* src = ei;
    const int* dst = ei + E;
    if (tid < nbuck) h[tid] = 0;

    // weight transposes spread over the grid's first 28672 threads
    int tg = blk * 256 + tid;
    if (tg < HID * KP) {
        int n = tg / KP, k = tg % KP;
        W1t[tg] = f2bf(k < KIN ? W1[(size_t)k * HID + n] : 0.0f);
    } else {
        int t2 = tg - HID * KP;
        if (t2 < HID * HID) {
            int n = t2 / HID, k = t2 % HID;
            W2t[t2] = f2bf(W2[(size_t)k * HID + n]);
        }
    }
    __syncthreads();

    const int chunk = (E + NPB - 1) / NPB;
    const int beg = blk * chunk, end = min(beg + chunk, E);
    for (int i = beg + tid; i < end; i += 256) {
        int d = dst[i];
        atomicAdd(&h[d >> BSH], 1);
        outE[i] = (float)src[i];
        outE[E + i] = (float)d;
    }
    __syncthreads();
    if (tid < nbuck) histG[tid * NPB + blk] = h[tid];
}

// ---- p2a: per-bucket exclusive scan of its NPB counts + totals ----
__global__ __launch_bounds__(NPB) void p2a_kernel(
    int* __restrict__ histG, int* __restrict__ totals)
{
    __shared__ int wsum[NPB / 64];
    const int b = blockIdx.x, tid = threadIdx.x, lane = tid & 63, wid = tid >> 6;
    int c = histG[b * NPB + tid];
    int s = c;
#pragma unroll
    for (int off = 1; off < 64; off <<= 1) {
        int t = __shfl_up(s, off, 64);
        if (lane >= off) s += t;
    }
    if (lane == 63) wsum[wid] = s;
    __syncthreads();
    if (tid == 0) {
        int a = 0;
#pragma unroll
        for (int w = 0; w < NPB / 64; ++w) { int t = wsum[w]; wsum[w] = a; a += t; }
    }
    __syncthreads();
    int excl = wsum[wid] + s - c;
    histG[b * NPB + tid] = excl;
    if (tid == NPB - 1) totals[b] = excl + c;
}

// In-block exclusive scan of totals[0..nbuck) -> sexcl[tid] (256 threads).
static __device__ inline void scan_totals(const int* __restrict__ totals,
                                          int* __restrict__ sexcl,
                                          int* __restrict__ wsum,
                                          int nbuck, int tid)
{
    const int lane = tid & 63, wid = tid >> 6;
    int v = (tid < nbuck) ? totals[tid] : 0;
    int s = v;
#pragma unroll
    for (int off = 1; off < 64; off <<= 1) {
        int t = __shfl_up(s, off, 64);
        if (lane >= off) s += t;
    }
    if (lane == 63) wsum[wid] = s;
    __syncthreads();
    if (tid == 0) {
        int a = 0;
#pragma unroll
        for (int w = 0; w < 4; ++w) { int t = wsum[w]; wsum[w] = a; a += t; }
    }
    __syncthreads();
    sexcl[tid] = wsum[wid] + s - v;
}

// ---- p3: partition edges into bucket-contiguous ebuf ----
__global__ __launch_bounds__(256) void p3_part_kernel(
    const int* __restrict__ ei, const int* __restrict__ histG,
    const int* __restrict__ totals, unsigned* __restrict__ ebuf,
    int E, int nbuck)
{
    __shared__ int cur[MAXBUCK];
    __shared__ int wsum[4];
    const int tid = threadIdx.x, blk = blockIdx.x;
    const int* src = ei;
    const int* dst = ei + E;
    scan_totals(totals, cur, wsum, nbuck, tid);   // cur[tid] = bucket base
    __syncthreads();
    if (tid < nbuck) cur[tid] += histG[tid * NPB + blk];
    const int chunk = (E + NPB - 1) / NPB;
    const int beg = blk * chunk, end = min(beg + chunk, E);
    __syncthreads();
    for (int i = beg + tid; i < end; i += 256) {
        int d = dst[i];
        int b = d >> BSH;
        int pos = atomicAdd(&cur[b], 1);
        ebuf[pos] = ((unsigned)(d & (BNODES - 1)) << 16) | (unsigned)src[i];
    }
}

// ---- p4: per-bucket sort -> csr, rowptr, dis, Xhs = bf16(dis*X) ----
__global__ __launch_bounds__(256) void p4_sort_kernel(
    const unsigned* __restrict__ ebuf, const int* __restrict__ totals,
    unsigned short* __restrict__ csr, int* __restrict__ rowptr,
    float* __restrict__ dis, const float* __restrict__ X,
    unsigned* __restrict__ Xhs, int N, int E, int nbuck)
{
    __shared__ int counts[BNODES];
    __shared__ int cursor[BNODES];
    __shared__ int sbase[MAXBUCK];
    __shared__ int wsum[4];
    __shared__ float sdis[BNODES];
    __shared__ unsigned short staging[P4CAP];
    const int b = blockIdx.x, tid = threadIdx.x, lane = tid & 63, wid = tid >> 6;

    scan_totals(totals, sbase, wsum, nbuck, tid);
    __syncthreads();
    const int gbase = sbase[b];
    const int cnt = totals[b];

    counts[tid] = 0;
    __syncthreads();
    for (int i = tid; i < cnt; i += 256)
        atomicAdd(&counts[ebuf[gbase + i] >> 16], 1);
    __syncthreads();

    int c = counts[tid];
    int s = c;
#pragma unroll
    for (int off = 1; off < 64; off <<= 1) {
        int t = __shfl_up(s, off, 64);
        if (lane >= off) s += t;
    }
    if (lane == 63) wsum[wid] = s;
    __syncthreads();
    if (tid == 0) {
        int a = 0;
#pragma unroll
        for (int w = 0; w < 4; ++w) { int t = wsum[w]; wsum[w] = a; a += t; }
    }
    __syncthreads();
    int excl = wsum[wid] + s - c;
    cursor[tid] = excl;
    float dd = rsqrtf(1.0f + (float)c);
    sdis[tid] = dd;
    int node = b * BNODES + tid;
    if (node < N) {
        rowptr[node] = gbase + excl;
        dis[node] = dd;
    }
    if (b == 0 && tid == 0) rowptr[N] = E;
    __syncthreads();

    if (cnt <= P4CAP) {
        for (int i = tid; i < cnt; i += 256) {
            unsigned v = ebuf[gbase + i];
            int pos = atomicAdd(&cursor[v >> 16], 1);
            staging[pos] = (unsigned short)(v & 0xFFFFu);
        }
        __syncthreads();
        for (int i = tid; i < cnt; i += 256)
            csr[gbase + i] = staging[i];
    } else {
        for (int i = tid; i < cnt; i += 256) {
            unsigned v = ebuf[gbase + i];
            int pos = atomicAdd(&cursor[v >> 16], 1);
            csr[gbase + pos] = (unsigned short)(v & 0xFFFFu);
        }
    }

    // Xhs = bf16(dis * X) for this bucket's nodes (coalesced)
    const int nodeBase = b * BNODES;
    for (int idx = tid; idx < BNODES * (KP / 2); idx += 256) {
        int nl = idx / (KP / 2), cc = idx % (KP / 2);
        int nd = nodeBase + nl;
        if (nd < N) {
            const float* xr = X + (size_t)nd * KIN;
            float d = sdis[nl];
            float a = (2 * cc     < KIN) ? d * xr[2 * cc]     : 0.0f;
            float bb = (2 * cc + 1 < KIN) ? d * xr[2 * cc + 1] : 0.0f;
            Xhs[(size_t)nd * (KP / 2) + cc] = pack_bf16(a, bb);
        }
    }
}

// ---- gather_x: one wave per node, raw sum of pre-scaled rows ----
__global__ __launch_bounds__(256) void gather_x_kernel(
    const unsigned* __restrict__ rows, const int* __restrict__ rowptr,
    const unsigned short* __restrict__ csr, unsigned* __restrict__ aggh, int N)
{
    int node = blockIdx.x * 4 + (threadIdx.x >> 6);
    if (node >= N) return;
    int lane = threadIdx.x & 63;
    bool act = lane < (KP / 2);

    float a0 = 0.0f, a1 = 0.0f;
    if (act) {
        float2 v = unpack_bf16(rows[(size_t)node * (KP / 2) + lane]);  // self
        a0 = v.x; a1 = v.y;
    }

    int beg = rowptr[node], end = rowptr[node + 1];
    int j = beg;
    for (; j + 4 <= end; j += 4) {
        int s0 = csr[j], s1 = csr[j + 1], s2 = csr[j + 2], s3 = csr[j + 3];
        if (act) {
            float2 v0 = unpack_bf16(rows[(size_t)s0 * (KP / 2) + lane]);
            float2 v1 = unpack_bf16(rows[(size_t)s1 * (KP / 2) + lane]);
            float2 v2 = unpack_bf16(rows[(size_t)s2 * (KP / 2) + lane]);
            float2 v3 = unpack_bf16(rows[(size_t)s3 * (KP / 2) + lane]);
            a0 += v0.x + v1.x + v2.x + v3.x;
            a1 += v0.y + v1.y + v2.y + v3.y;
        }
    }
    for (; j < end; ++j) {
        int sx = csr[j];
        if (act) {
            float2 v = unpack_bf16(rows[(size_t)sx * (KP / 2) + lane]);
            a0 += v.x; a1 += v.y;
        }
    }
    if (act)
        aggh[(size_t)node * (KP / 2) + lane] = pack_bf16(a0, a1);
}

// ---- gather_h: one wave per node over g2h [N][128], raw sum ----
__global__ __launch_bounds__(256) void gather_h_kernel(
    const unsigned* __restrict__ rows, const int* __restrict__ rowptr,
    const unsigned short* __restrict__ csr, unsigned* __restrict__ aggh, int N)
{
    int node = blockIdx.x * 4 + (threadIdx.x >> 6);
    if (node >= N) return;
    int lane = threadIdx.x & 63;
    int beg = rowptr[node], end = rowptr[node + 1];

    float2 sv = unpack_bf16(rows[(size_t)node * (HID / 2) + lane]);  // self
    float a0 = sv.x, a1 = sv.y;
    int j = beg;
    for (; j + 4 <= end; j += 4) {
        int s0 = csr[j], s1 = csr[j + 1], s2 = csr[j + 2], s3 = csr[j + 3];
        float2 v0 = unpack_bf16(rows[(size_t)s0 * (HID / 2) + lane]);
        float2 v1 = unpack_bf16(rows[(size_t)s1 * (HID / 2) + lane]);
        float2 v2 = unpack_bf16(rows[(size_t)s2 * (HID / 2) + lane]);
        float2 v3 = unpack_bf16(rows[(size_t)s3 * (HID / 2) + lane]);
        a0 += v0.x + v1.x + v2.x + v3.x;
        a1 += v0.y + v1.y + v2.y + v3.y;
    }
    for (; j < end; ++j) {
        int sx = csr[j];
        float2 v = unpack_bf16(rows[(size_t)sx * (HID / 2) + lane]);
        a0 += v.x; a1 += v.y;
    }
    aggh[(size_t)node * (HID / 2) + lane] = pack_bf16(a0, a1);
}

// ---- MFMA GEMM (no LDS, transposed-D epilogue) ----
// Block = 64 nodes (4 waves x 16), wave covers 128 cols as 8 16x16 tiles.
// mfma(Wt-frag, node-frag) -> lane (m,quad) holds node=row0+m,
// cols t*16+quad*4+{0..3} -> vectorized stores.
//   LAYER1: store bf16( relu(d*acc + b) * d )     (pre-scaled rows for layer 2)
//   LAYER2: store fp32( relu(d*acc + b) )
template<int KPA, bool LAYER1>
__global__ __launch_bounds__(256) void mfma_gemm_kernel(
    const unsigned short* __restrict__ A, const unsigned short* __restrict__ Wt,
    const float* __restrict__ bias, const float* __restrict__ dis,
    void* __restrict__ outp, int N)
{
    const int wave = threadIdx.x >> 6;
    const int lane = threadIdx.x & 63;
    const int m    = lane & 15;
    const int quad = lane >> 4;
    const int row0 = blockIdx.x * 64 + wave * 16;
    const int node = row0 + m;

    f32x4 acc[8];
#pragma unroll
    for (int t = 0; t < 8; ++t) acc[t] = (f32x4){0.0f, 0.0f, 0.0f, 0.0f};

    const int arow = min(node, N - 1);           // clamp: stores are guarded
    const unsigned short* arp = A + (size_t)arow * KPA;

#pragma unroll
    for (int c = 0; c < KPA / 32; ++c) {
        const int k0 = c * 32 + quad * 8;
        bf16x8 nv = *(const bf16x8*)(arp + k0);                      // B-frag
#pragma unroll
        for (int t = 0; t < 8; ++t) {
            bf16x8 wv = *(const bf16x8*)(Wt + (size_t)(t * 16 + m) * KPA + k0);  // A-frag
            acc[t] = __builtin_amdgcn_mfma_f32_16x16x32_bf16(wv, nv, acc[t], 0, 0, 0);
        }
    }

    if (node < N) {
        const float dv = dis[node];
#pragma unroll
        for (int t = 0; t < 8; ++t) {
            const int col0 = t * 16 + quad * 4;
            float4 bb = *(const float4*)&bias[col0];
            float r0 = fmaxf(fmaf(dv, acc[t][0], bb.x), 0.0f);
            float r1 = fmaxf(fmaf(dv, acc[t][1], bb.y), 0.0f);
            float r2 = fmaxf(fmaf(dv, acc[t][2], bb.z), 0.0f);
            float r3 = fmaxf(fmaf(dv, acc[t][3], bb.w), 0.0f);
            if (LAYER1) {
                uint2 u;
                u.x = pack_bf16(r0 * dv, r1 * dv);
                u.y = pack_bf16(r2 * dv, r3 * dv);
                *(uint2*)((unsigned short*)outp + (size_t)node * HID + col0) = u;
            } else {
                float4 r = make_float4(r0, r1, r2, r3);
                *(float4*)((float*)outp + (size_t)node * HID + col0) = r;
            }
        }
    }
}

// ---------------- launch ----------------

static inline char* wsal(char*& p, size_t n) {
    uintptr_t q = ((uintptr_t)p + 255) & ~(uintptr_t)255;
    char* r = (char*)q;
    p = r + n;
    return r;
}

extern "C" void kernel_launch(void* const* d_in, const int* in_sizes, int n_in,
                              void* d_out, int out_size, void* d_ws, size_t ws_size,
                              hipStream_t stream) {
    const float* x  = (const float*)d_in[0];
    const int*   ei = (const int*)d_in[1];
    const float* W1 = (const float*)d_in[2];
    const float* b1 = (const float*)d_in[3];
    const float* W2 = (const float*)d_in[4];
    const float* b2 = (const float*)d_in[5];

    const int N = in_sizes[0] / KIN;  // 50000  (< 65536 required)
    const int E = in_sizes[1] / 2;    // 800000
    const int nbuck = (N + BNODES - 1) >> BSH;   // 196 (<= MAXBUCK)

    float* out  = (float*)d_out;
    float* outH = out;                      // [N,128] final fp32 output
    float* outE = out + (size_t)N * HID;    // [2,E] edge_index as float

    char* ws = (char*)d_ws;
    int*            histG  = (int*)wsal(ws, (size_t)MAXBUCK * NPB * 4);
    int*            totals = (int*)wsal(ws, MAXBUCK * 4);
    int*            rowptr = (int*)wsal(ws, (size_t)(N + 1) * 4);
    float*          dis    = (float*)wsal(ws, (size_t)N * 4);
    unsigned*       ebuf   = (unsigned*)wsal(ws, (size_t)E * 4);
    unsigned short* csr    = (unsigned short*)wsal(ws, (size_t)E * 2);
    unsigned*       Xhs    = (unsigned*)wsal(ws, (size_t)N * (KP / 2) * 4);
    unsigned*       agg1h  = (unsigned*)wsal(ws, (size_t)N * (KP / 2) * 4);
    unsigned short* g2h    = (unsigned short*)wsal(ws, (size_t)N * HID * 2);
    unsigned short* agg2h  = (unsigned short*)wsal(ws, (size_t)N * HID * 2);
    unsigned short* W1t    = (unsigned short*)wsal(ws, (size_t)HID * KP * 2);
    unsigned short* W2t    = (unsigned short*)wsal(ws, (size_t)HID * HID * 2);

    p1_kernel<<<NPB, 256, 0, stream>>>(ei, outE, histG, W1, W1t, W2, W2t, E, nbuck);
    p2a_kernel<<<nbuck, NPB, 0, stream>>>(histG, totals);
    p3_part_kernel<<<NPB, 256, 0, stream>>>(ei, histG, totals, ebuf, E, nbuck);
    p4_sort_kernel<<<nbuck, 256, 0, stream>>>(ebuf, totals, csr, rowptr, dis,
                                              x, Xhs, N, E, nbuck);

    const int ngt = (N + 3) / 4;
    const int ngm = (N + 63) / 64;

    // Layer 1
    gather_x_kernel<<<ngt, 256, 0, stream>>>(Xhs, rowptr, csr, agg1h, N);
    mfma_gemm_kernel<KP, true><<<ngm, 256, 0, stream>>>(
        (const unsigned short*)agg1h, W1t, b1, dis, g2h, N);

    // Layer 2
    gather_h_kernel<<<ngt, 256, 0, stream>>>((const unsigned*)g2h, rowptr, csr,
                                             (unsigned*)agg2h, N);
    mfma_gemm_kernel<HID, false><<<ngm, 256, 0, stream>>>(
        agg2h, W2t, b2, dis, outH, N);
}

// Round 10
// 234.474 us; speedup vs baseline: 1.1446x; 1.0718x over previous
//
#include <hip/hip_runtime.h>
#include <hip/hip_bf16.h>

// GCN 2-layer, 9 launches.
//   p1    : bucket histogram + edge_index copy-out + W1/W2 transpose->bf16
//   p2a   : scan of per-partition bucket counts
//   p3    : partition edges into bucket-contiguous ebuf
//   p4    : per-bucket counting sort -> csr(ushort), rowptr, dis
//   xconv : Xhs = bf16(dis*X) [N][96]   (full-occupancy streaming kernel)
//   gather_x : agg1h = bf16( Xhs_i + sum_s Xhs_s )           (raw sum)
//   gemm1    : g2h   = bf16( relu(d*(agg1h@W1t) + b1) * d )  (MFMA, no LDS)
//   gather_h : agg2h = bf16( g2h_i + sum_s g2h_s )           (raw sum)
//   gemm2    : out   = relu( d*(agg2h@W2t) + b2 )            fp32
// All row operands bf16 (fp32 accumulation). Requires N < 65536.

#define HID 128
#define KIN 89
#define KP 96     // padded input dim
#define BSH 8     // bucket = 256 nodes
#define BNODES 256
#define MAXBUCK 256
#define NPB 128       // partition blocks
#define P4CAP 6144    // staging capacity per bucket (mean ~4081)

typedef __attribute__((ext_vector_type(8))) short bf16x8;
typedef __attribute__((ext_vector_type(4))) float f32x4;

static __device__ inline float2 unpack_bf16(unsigned v) {
    union { unsigned u; float f; } lo, hi;
    lo.u = v << 16;
    hi.u = v & 0xFFFF0000u;
    return make_float2(lo.f, hi.f);
}

static __device__ inline unsigned pack_bf16(float a, float b) {
    __hip_bfloat162 h = __float22bfloat162_rn(make_float2(a, b));
    return *reinterpret_cast<unsigned*>(&h);
}

static __device__ inline unsigned short f2bf(float v) {
    __hip_bfloat16 h = __float2bfloat16(v);
    return *reinterpret_cast<unsigned short*>(&h);
}

// ---- p1: histogram + edge copy + weight transposes ----
__global__ __launch_bounds__(256) void p1_kernel(
    const int* __restrict__ ei, float* __restrict__ outE,
    int* __restrict__ histG,
    const float* __restrict__ W1, unsigned short* __restrict__ W1t,
    const float* __restrict__ W2, unsigned short* __restrict__ W2t,
    int E, int nbuck)
{
    __shared__ int h[MAXBUCK];
    const int tid = threadIdx.x, blk = blockIdx.x;
    const int* src = ei;
    const int* dst = ei + E;
    if (tid < nbuck) h[tid] = 0;

    // weight transposes spread over the grid's first 28672 threads
    int tg = blk * 256 + tid;
    if (tg < HID * KP) {
        int n = tg / KP, k = tg % KP;
        W1t[tg] = f2bf(k < KIN ? W1[(size_t)k * HID + n] : 0.0f);
    } else {
        int t2 = tg - HID * KP;
        if (t2 < HID * HID) {
            int n = t2 / HID, k = t2 % HID;
            W2t[t2] = f2bf(W2[(size_t)k * HID + n]);
        }
    }
    __syncthreads();

    const int chunk = (E + NPB - 1) / NPB;
    const int beg = blk * chunk, end = min(beg + chunk, E);
    for (int i = beg + tid; i < end; i += 256) {
        int d = dst[i];
        atomicAdd(&h[d >> BSH], 1);
        outE[i] = (float)src[i];
        outE[E + i] = (float)d;
    }
    __syncthreads();
    if (tid < nbuck) histG[tid * NPB + blk] = h[tid];
}

// ---- p2a: per-bucket exclusive scan of its NPB counts + totals ----
__global__ __launch_bounds__(NPB) void p2a_kernel(
    int* __restrict__ histG, int* __restrict__ totals)
{
    __shared__ int wsum[NPB / 64];
    const int b = blockIdx.x, tid = threadIdx.x, lane = tid & 63, wid = tid >> 6;
    int c = histG[b * NPB + tid];
    int s = c;
#pragma unroll
    for (int off = 1; off < 64; off <<= 1) {
        int t = __shfl_up(s, off, 64);
        if (lane >= off) s += t;
    }
    if (lane == 63) wsum[wid] = s;
    __syncthreads();
    if (tid == 0) {
        int a = 0;
#pragma unroll
        for (int w = 0; w < NPB / 64; ++w) { int t = wsum[w]; wsum[w] = a; a += t; }
    }
    __syncthreads();
    int excl = wsum[wid] + s - c;
    histG[b * NPB + tid] = excl;
    if (tid == NPB - 1) totals[b] = excl + c;
}

// In-block exclusive scan of totals[0..nbuck) -> sexcl[tid] (256 threads).
static __device__ inline void scan_totals(const int* __restrict__ totals,
                                          int* __restrict__ sexcl,
                                          int* __restrict__ wsum,
                                          int nbuck, int tid)
{
    const int lane = tid & 63, wid = tid >> 6;
    int v = (tid < nbuck) ? totals[tid] : 0;
    int s = v;
#pragma unroll
    for (int off = 1; off < 64; off <<= 1) {
        int t = __shfl_up(s, off, 64);
        if (lane >= off) s += t;
    }
    if (lane == 63) wsum[wid] = s;
    __syncthreads();
    if (tid == 0) {
        int a = 0;
#pragma unroll
        for (int w = 0; w < 4; ++w) { int t = wsum[w]; wsum[w] = a; a += t; }
    }
    __syncthreads();
    sexcl[tid] = wsum[wid] + s - v;
}

// ---- p3: partition edges into bucket-contiguous ebuf ----
__global__ __launch_bounds__(256) void p3_part_kernel(
    const int* __restrict__ ei, const int* __restrict__ histG,
    const int* __restrict__ totals, unsigned* __restrict__ ebuf,
    int E, int nbuck)
{
    __shared__ int cur[MAXBUCK];
    __shared__ int wsum[4];
    const int tid = threadIdx.x, blk = blockIdx.x;
    const int* src = ei;
    const int* dst = ei + E;
    scan_totals(totals, cur, wsum, nbuck, tid);   // cur[tid] = bucket base
    __syncthreads();
    if (tid < nbuck) cur[tid] += histG[tid * NPB + blk];
    const int chunk = (E + NPB - 1) / NPB;
    const int beg = blk * chunk, end = min(beg + chunk, E);
    __syncthreads();
    for (int i = beg + tid; i < end; i += 256) {
        int d = dst[i];
        int b = d >> BSH;
        int pos = atomicAdd(&cur[b], 1);
        ebuf[pos] = ((unsigned)(d & (BNODES - 1)) << 16) | (unsigned)src[i];
    }
}

// ---- p4: per-bucket sort -> csr, rowptr, dis ----
__global__ __launch_bounds__(256) void p4_sort_kernel(
    const unsigned* __restrict__ ebuf, const int* __restrict__ totals,
    unsigned short* __restrict__ csr, int* __restrict__ rowptr,
    float* __restrict__ dis, int N, int E, int nbuck)
{
    __shared__ int counts[BNODES];
    __shared__ int cursor[BNODES];
    __shared__ int sbase[MAXBUCK];
    __shared__ int wsum[4];
    __shared__ unsigned short staging[P4CAP];
    const int b = blockIdx.x, tid = threadIdx.x, lane = tid & 63, wid = tid >> 6;

    scan_totals(totals, sbase, wsum, nbuck, tid);
    __syncthreads();
    const int gbase = sbase[b];
    const int cnt = totals[b];

    counts[tid] = 0;
    __syncthreads();
    for (int i = tid; i < cnt; i += 256)
        atomicAdd(&counts[ebuf[gbase + i] >> 16], 1);
    __syncthreads();

    int c = counts[tid];
    int s = c;
#pragma unroll
    for (int off = 1; off < 64; off <<= 1) {
        int t = __shfl_up(s, off, 64);
        if (lane >= off) s += t;
    }
    if (lane == 63) wsum[wid] = s;
    __syncthreads();
    if (tid == 0) {
        int a = 0;
#pragma unroll
        for (int w = 0; w < 4; ++w) { int t = wsum[w]; wsum[w] = a; a += t; }
    }
    __syncthreads();
    int excl = wsum[wid] + s - c;
    cursor[tid] = excl;
    int node = b * BNODES + tid;
    if (node < N) {
        rowptr[node] = gbase + excl;
        dis[node] = rsqrtf(1.0f + (float)c);
    }
    if (b == 0 && tid == 0) rowptr[N] = E;
    __syncthreads();

    if (cnt <= P4CAP) {
        for (int i = tid; i < cnt; i += 256) {
            unsigned v = ebuf[gbase + i];
            int pos = atomicAdd(&cursor[v >> 16], 1);
            staging[pos] = (unsigned short)(v & 0xFFFFu);
        }
        __syncthreads();
        for (int i = tid; i < cnt; i += 256)
            csr[gbase + i] = staging[i];
    } else {
        for (int i = tid; i < cnt; i += 256) {
            unsigned v = ebuf[gbase + i];
            int pos = atomicAdd(&cursor[v >> 16], 1);
            csr[gbase + pos] = (unsigned short)(v & 0xFFFFu);
        }
    }
}

// ---- xconv: Xhs = bf16(dis * X), full-occupancy streaming ----
__global__ __launch_bounds__(256) void xconv_kernel(
    const float* __restrict__ X, const float* __restrict__ dis,
    unsigned* __restrict__ Xhs, int N)
{
    int t = blockIdx.x * 256 + threadIdx.x;
    if (t >= N * (KP / 2)) return;
    int n = t / (KP / 2), c = t % (KP / 2);
    float d = dis[n];
    const float* xr = X + (size_t)n * KIN;
    float a = (2 * c     < KIN) ? d * xr[2 * c]     : 0.0f;
    float b = (2 * c + 1 < KIN) ? d * xr[2 * c + 1] : 0.0f;
    Xhs[t] = pack_bf16(a, b);
}

// ---- gather_x: one wave per node, raw sum of pre-scaled rows ----
__global__ __launch_bounds__(256) void gather_x_kernel(
    const unsigned* __restrict__ rows, const int* __restrict__ rowptr,
    const unsigned short* __restrict__ csr, unsigned* __restrict__ aggh, int N)
{
    int node = blockIdx.x * 4 + (threadIdx.x >> 6);
    if (node >= N) return;
    int lane = threadIdx.x & 63;
    bool act = lane < (KP / 2);

    float a0 = 0.0f, a1 = 0.0f;
    if (act) {
        float2 v = unpack_bf16(rows[(size_t)node * (KP / 2) + lane]);  // self
        a0 = v.x; a1 = v.y;
    }

    int beg = rowptr[node], end = rowptr[node + 1];
    int j = beg;
    for (; j + 4 <= end; j += 4) {
        int s0 = csr[j], s1 = csr[j + 1], s2 = csr[j + 2], s3 = csr[j + 3];
        if (act) {
            float2 v0 = unpack_bf16(rows[(size_t)s0 * (KP / 2) + lane]);
            float2 v1 = unpack_bf16(rows[(size_t)s1 * (KP / 2) + lane]);
            float2 v2 = unpack_bf16(rows[(size_t)s2 * (KP / 2) + lane]);
            float2 v3 = unpack_bf16(rows[(size_t)s3 * (KP / 2) + lane]);
            a0 += v0.x + v1.x + v2.x + v3.x;
            a1 += v0.y + v1.y + v2.y + v3.y;
        }
    }
    for (; j < end; ++j) {
        int sx = csr[j];
        if (act) {
            float2 v = unpack_bf16(rows[(size_t)sx * (KP / 2) + lane]);
            a0 += v.x; a1 += v.y;
        }
    }
    if (act)
        aggh[(size_t)node * (KP / 2) + lane] = pack_bf16(a0, a1);
}

// ---- gather_h: one wave per node over g2h [N][128], raw sum ----
__global__ __launch_bounds__(256) void gather_h_kernel(
    const unsigned* __restrict__ rows, const int* __restrict__ rowptr,
    const unsigned short* __restrict__ csr, unsigned* __restrict__ aggh, int N)
{
    int node = blockIdx.x * 4 + (threadIdx.x >> 6);
    if (node >= N) return;
    int lane = threadIdx.x & 63;
    int beg = rowptr[node], end = rowptr[node + 1];

    float2 sv = unpack_bf16(rows[(size_t)node * (HID / 2) + lane]);  // self
    float a0 = sv.x, a1 = sv.y;
    int j = beg;
    for (; j + 4 <= end; j += 4) {
        int s0 = csr[j], s1 = csr[j + 1], s2 = csr[j + 2], s3 = csr[j + 3];
        float2 v0 = unpack_bf16(rows[(size_t)s0 * (HID / 2) + lane]);
        float2 v1 = unpack_bf16(rows[(size_t)s1 * (HID / 2) + lane]);
        float2 v2 = unpack_bf16(rows[(size_t)s2 * (HID / 2) + lane]);
        float2 v3 = unpack_bf16(rows[(size_t)s3 * (HID / 2) + lane]);
        a0 += v0.x + v1.x + v2.x + v3.x;
        a1 += v0.y + v1.y + v2.y + v3.y;
    }
    for (; j < end; ++j) {
        int sx = csr[j];
        float2 v = unpack_bf16(rows[(size_t)sx * (HID / 2) + lane]);
        a0 += v.x; a1 += v.y;
    }
    aggh[(size_t)node * (HID / 2) + lane] = pack_bf16(a0, a1);
}

// ---- MFMA GEMM (no LDS, transposed-D epilogue) ----
// Block = 64 nodes (4 waves x 16), wave covers 128 cols as 8 16x16 tiles.
// mfma(Wt-frag, node-frag) -> lane (m,quad) holds node=row0+m,
// cols t*16+quad*4+{0..3} -> vectorized stores.
//   LAYER1: store bf16( relu(d*acc + b) * d )     (pre-scaled rows for layer 2)
//   LAYER2: store fp32( relu(d*acc + b) )
template<int KPA, bool LAYER1>
__global__ __launch_bounds__(256) void mfma_gemm_kernel(
    const unsigned short* __restrict__ A, const unsigned short* __restrict__ Wt,
    const float* __restrict__ bias, const float* __restrict__ dis,
    void* __restrict__ outp, int N)
{
    const int wave = threadIdx.x >> 6;
    const int lane = threadIdx.x & 63;
    const int m    = lane & 15;
    const int quad = lane >> 4;
    const int row0 = blockIdx.x * 64 + wave * 16;
    const int node = row0 + m;

    f32x4 acc[8];
#pragma unroll
    for (int t = 0; t < 8; ++t) acc[t] = (f32x4){0.0f, 0.0f, 0.0f, 0.0f};

    const int arow = min(node, N - 1);           // clamp: stores are guarded
    const unsigned short* arp = A + (size_t)arow * KPA;

#pragma unroll
    for (int c = 0; c < KPA / 32; ++c) {
        const int k0 = c * 32 + quad * 8;
        bf16x8 nv = *(const bf16x8*)(arp + k0);                      // B-frag
#pragma unroll
        for (int t = 0; t < 8; ++t) {
            bf16x8 wv = *(const bf16x8*)(Wt + (size_t)(t * 16 + m) * KPA + k0);  // A-frag
            acc[t] = __builtin_amdgcn_mfma_f32_16x16x32_bf16(wv, nv, acc[t], 0, 0, 0);
        }
    }

    if (node < N) {
        const float dv = dis[node];
#pragma unroll
        for (int t = 0; t < 8; ++t) {
            const int col0 = t * 16 + quad * 4;
            float4 bb = *(const float4*)&bias[col0];
            float r0 = fmaxf(fmaf(dv, acc[t][0], bb.x), 0.0f);
            float r1 = fmaxf(fmaf(dv, acc[t][1], bb.y), 0.0f);
            float r2 = fmaxf(fmaf(dv, acc[t][2], bb.z), 0.0f);
            float r3 = fmaxf(fmaf(dv, acc[t][3], bb.w), 0.0f);
            if (LAYER1) {
                uint2 u;
                u.x = pack_bf16(r0 * dv, r1 * dv);
                u.y = pack_bf16(r2 * dv, r3 * dv);
                *(uint2*)((unsigned short*)outp + (size_t)node * HID + col0) = u;
            } else {
                float4 r = make_float4(r0, r1, r2, r3);
                *(float4*)((float*)outp + (size_t)node * HID + col0) = r;
            }
        }
    }
}

// ---------------- launch ----------------

static inline char* wsal(char*& p, size_t n) {
    uintptr_t q = ((uintptr_t)p + 255) & ~(uintptr_t)255;
    char* r = (char*)q;
    p = r + n;
    return r;
}

extern "C" void kernel_launch(void* const* d_in, const int* in_sizes, int n_in,
                              void* d_out, int out_size, void* d_ws, size_t ws_size,
                              hipStream_t stream) {
    const float* x  = (const float*)d_in[0];
    const int*   ei = (const int*)d_in[1];
    const float* W1 = (const float*)d_in[2];
    const float* b1 = (const float*)d_in[3];
    const float* W2 = (const float*)d_in[4];
    const float* b2 = (const float*)d_in[5];

    const int N = in_sizes[0] / KIN;  // 50000  (< 65536 required)
    const int E = in_sizes[1] / 2;    // 800000
    const int nbuck = (N + BNODES - 1) >> BSH;   // 196 (<= MAXBUCK)

    float* out  = (float*)d_out;
    float* outH = out;                      // [N,128] final fp32 output
    float* outE = out + (size_t)N * HID;    // [2,E] edge_index as float

    char* ws = (char*)d_ws;
    int*            histG  = (int*)wsal(ws, (size_t)MAXBUCK * NPB * 4);
    int*            totals = (int*)wsal(ws, MAXBUCK * 4);
    int*            rowptr = (int*)wsal(ws, (size_t)(N + 1) * 4);
    float*          dis    = (float*)wsal(ws, (size_t)N * 4);
    unsigned*       ebuf   = (unsigned*)wsal(ws, (size_t)E * 4);
    unsigned short* csr    = (unsigned short*)wsal(ws, (size_t)E * 2);
    unsigned*       Xhs    = (unsigned*)wsal(ws, (size_t)N * (KP / 2) * 4);
    unsigned*       agg1h  = (unsigned*)wsal(ws, (size_t)N * (KP / 2) * 4);
    unsigned short* g2h    = (unsigned short*)wsal(ws, (size_t)N * HID * 2);
    unsigned short* agg2h  = (unsigned short*)wsal(ws, (size_t)N * HID * 2);
    unsigned short* W1t    = (unsigned short*)wsal(ws, (size_t)HID * KP * 2);
    unsigned short* W2t    = (unsigned short*)wsal(ws, (size_t)HID * HID * 2);

    p1_kernel<<<NPB, 256, 0, stream>>>(ei, outE, histG, W1, W1t, W2, W2t, E, nbuck);
    p2a_kernel<<<nbuck, NPB, 0, stream>>>(histG, totals);
    p3_part_kernel<<<NPB, 256, 0, stream>>>(ei, histG, totals, ebuf, E, nbuck);
    p4_sort_kernel<<<nbuck, 256, 0, stream>>>(ebuf, totals, csr, rowptr, dis,
                                              N, E, nbuck);
    xconv_kernel<<<(N * (KP / 2) + 255) / 256, 256, 0, stream>>>(x, dis, Xhs, N);

    const int ngt = (N + 3) / 4;
    const int ngm = (N + 63) / 64;

    // Layer 1
    gather_x_kernel<<<ngt, 256, 0, stream>>>(Xhs, rowptr, csr, agg1h, N);
    mfma_gemm_kernel<KP, true><<<ngm, 256, 0, stream>>>(
        (const unsigned short*)agg1h, W1t, b1, dis, g2h, N);

    // Layer 2
    gather_h_kernel<<<ngt, 256, 0, stream>>>((const unsigned*)g2h, rowptr, csr,
                                             (unsigned*)agg2h, N);
    mfma_gemm_kernel<HID, false><<<ngm, 256, 0, stream>>>(
        agg2h, W2t, b2, dis, outH, N);
}

// Round 11
// 232.450 us; speedup vs baseline: 1.1546x; 1.0087x over previous
//
#include <hip/hip_runtime.h>
#include <hip/hip_bf16.h>

// GCN 2-layer, 9 launches. Buckets of 128 nodes (391 buckets) for 2x p4
// parallelism vs 256-node buckets.
//   p1    : bucket histogram + edge_index copy-out + W1/W2 transpose->bf16
//   p2a   : scan of per-partition bucket counts
//   p3    : partition edges into bucket-contiguous ebuf
//   p4    : per-bucket counting sort -> csr(ushort), rowptr, dis
//   xconv : Xhs = bf16(dis*X) [N][96]
//   gather_x : agg1h = bf16( Xhs_i + sum_s Xhs_s )           (raw sum)
//   gemm1    : g2h   = bf16( relu(d*(agg1h@W1t) + b1) * d )  (MFMA, no LDS)
//   gather_h : agg2h = bf16( g2h_i + sum_s g2h_s )           (raw sum)
//   gemm2    : out   = relu( d*(agg2h@W2t) + b2 )            fp32
// All row operands bf16 (fp32 accumulation). Requires N < 65536.

#define HID 128
#define KIN 89
#define KP 96     // padded input dim
#define BSH 7     // bucket = 128 nodes
#define BNODES 128
#define MAXBUCK 512   // capacity of bucket-indexed LDS/scan arrays
#define NPB 128       // partition blocks
#define P4CAP 3072    // staging capacity per bucket (mean ~2046, 5sd ~2270)

typedef __attribute__((ext_vector_type(8))) short bf16x8;
typedef __attribute__((ext_vector_type(4))) float f32x4;

static __device__ inline float2 unpack_bf16(unsigned v) {
    union { unsigned u; float f; } lo, hi;
    lo.u = v << 16;
    hi.u = v & 0xFFFF0000u;
    return make_float2(lo.f, hi.f);
}

static __device__ inline unsigned pack_bf16(float a, float b) {
    __hip_bfloat162 h = __float22bfloat162_rn(make_float2(a, b));
    return *reinterpret_cast<unsigned*>(&h);
}

static __device__ inline unsigned short f2bf(float v) {
    __hip_bfloat16 h = __float2bfloat16(v);
    return *reinterpret_cast<unsigned short*>(&h);
}

// ---- p1: histogram + edge copy + weight transposes ----
__global__ __launch_bounds__(256) void p1_kernel(
    const int* __restrict__ ei, float* __restrict__ outE,
    int* __restrict__ histG,
    const float* __restrict__ W1, unsigned short* __restrict__ W1t,
    const float* __restrict__ W2, unsigned short* __restrict__ W2t,
    int E, int nbuck)
{
    __shared__ int h[MAXBUCK];
    const int tid = threadIdx.x, blk = blockIdx.x;
    const int* src = ei;
    const int* dst = ei + E;
    for (int b = tid; b < nbuck; b += 256) h[b] = 0;

    // weight transposes spread over the grid's first 28672 threads
    int tg = blk * 256 + tid;
    if (tg < HID * KP) {
        int n = tg / KP, k = tg % KP;
        W1t[tg] = f2bf(k < KIN ? W1[(size_t)k * HID + n] : 0.0f);
    } else {
        int t2 = tg - HID * KP;
        if (t2 < HID * HID) {
            int n = t2 / HID, k = t2 % HID;
            W2t[t2] = f2bf(W2[(size_t)k * HID + n]);
        }
    }
    __syncthreads();

    const int chunk = (E + NPB - 1) / NPB;
    const int beg = blk * chunk, end = min(beg + chunk, E);
    for (int i = beg + tid; i < end; i += 256) {
        int d = dst[i];
        atomicAdd(&h[d >> BSH], 1);
        outE[i] = (float)src[i];
        outE[E + i] = (float)d;
    }
    __syncthreads();
    for (int b = tid; b < nbuck; b += 256) histG[b * NPB + blk] = h[b];
}

// ---- p2a: per-bucket exclusive scan of its NPB counts + totals ----
__global__ __launch_bounds__(NPB) void p2a_kernel(
    int* __restrict__ histG, int* __restrict__ totals)
{
    __shared__ int wsum[NPB / 64];
    const int b = blockIdx.x, tid = threadIdx.x, lane = tid & 63, wid = tid >> 6;
    int c = histG[b * NPB + tid];
    int s = c;
#pragma unroll
    for (int off = 1; off < 64; off <<= 1) {
        int t = __shfl_up(s, off, 64);
        if (lane >= off) s += t;
    }
    if (lane == 63) wsum[wid] = s;
    __syncthreads();
    if (tid == 0) {
        int a = 0;
#pragma unroll
        for (int w = 0; w < NPB / 64; ++w) { int t = wsum[w]; wsum[w] = a; a += t; }
    }
    __syncthreads();
    int excl = wsum[wid] + s - c;
    histG[b * NPB + tid] = excl;
    if (tid == NPB - 1) totals[b] = excl + c;
}

// In-block exclusive scan of totals[0..nbuck), nbuck <= 512, 256 threads.
// sexcl must have >= 512 entries.
static __device__ inline void scan_totals2(const int* __restrict__ totals,
                                           int* __restrict__ sexcl,
                                           int* __restrict__ wsum,
                                           int nbuck, int tid)
{
    const int lane = tid & 63, wid = tid >> 6;
    const int i0 = 2 * tid, i1 = 2 * tid + 1;
    int t0 = (i0 < nbuck) ? totals[i0] : 0;
    int t1 = (i1 < nbuck) ? totals[i1] : 0;
    int p = t0 + t1;
    int s = p;
#pragma unroll
    for (int off = 1; off < 64; off <<= 1) {
        int t = __shfl_up(s, off, 64);
        if (lane >= off) s += t;
    }
    if (lane == 63) wsum[wid] = s;
    __syncthreads();
    if (tid == 0) {
        int a = 0;
#pragma unroll
        for (int w = 0; w < 4; ++w) { int t = wsum[w]; wsum[w] = a; a += t; }
    }
    __syncthreads();
    int excl = wsum[wid] + s - p;
    sexcl[i0] = excl;
    sexcl[i1] = excl + t0;
}

// ---- p3: partition edges into bucket-contiguous ebuf ----
__global__ __launch_bounds__(256) void p3_part_kernel(
    const int* __restrict__ ei, const int* __restrict__ histG,
    const int* __restrict__ totals, unsigned* __restrict__ ebuf,
    int E, int nbuck)
{
    __shared__ int cur[MAXBUCK];
    __shared__ int wsum[4];
    const int tid = threadIdx.x, blk = blockIdx.x;
    const int* src = ei;
    const int* dst = ei + E;
    scan_totals2(totals, cur, wsum, nbuck, tid);   // cur[b] = bucket base
    __syncthreads();
    for (int b = tid; b < nbuck; b += 256) cur[b] += histG[b * NPB + blk];
    const int chunk = (E + NPB - 1) / NPB;
    const int beg = blk * chunk, end = min(beg + chunk, E);
    __syncthreads();
    for (int i = beg + tid; i < end; i += 256) {
        int d = dst[i];
        int b = d >> BSH;
        int pos = atomicAdd(&cur[b], 1);
        ebuf[pos] = ((unsigned)(d & (BNODES - 1)) << 16) | (unsigned)src[i];
    }
}

// ---- p4: per-bucket sort -> csr, rowptr, dis ----
__global__ __launch_bounds__(256) void p4_sort_kernel(
    const unsigned* __restrict__ ebuf, const int* __restrict__ totals,
    unsigned short* __restrict__ csr, int* __restrict__ rowptr,
    float* __restrict__ dis, int N, int E, int nbuck)
{
    __shared__ int counts[BNODES];
    __shared__ int cursor[BNODES];
    __shared__ int sbase[MAXBUCK];
    __shared__ int wsum[4];
    __shared__ int w2[2];
    __shared__ unsigned short staging[P4CAP];
    const int b = blockIdx.x, tid = threadIdx.x, lane = tid & 63, wid = tid >> 6;

    scan_totals2(totals, sbase, wsum, nbuck, tid);
    __syncthreads();
    const int gbase = sbase[b];
    const int cnt = totals[b];

    if (tid < BNODES) counts[tid] = 0;
    __syncthreads();
    for (int i = tid; i < cnt; i += 256)
        atomicAdd(&counts[ebuf[gbase + i] >> 16], 1);
    __syncthreads();

    // exclusive scan of BNODES=128 counts (first 2 waves)
    int c = 0, s = 0;
    if (tid < BNODES) {
        c = counts[tid];
        s = c;
#pragma unroll
        for (int off = 1; off < 64; off <<= 1) {
            int t = __shfl_up(s, off, 64);
            if (lane >= off) s += t;
        }
        if (lane == 63) w2[wid] = s;
    }
    __syncthreads();
    if (tid == 0) { int t = w2[0]; w2[0] = 0; w2[1] = t; }
    __syncthreads();
    if (tid < BNODES) {
        int excl = w2[wid] + s - c;
        cursor[tid] = excl;
        int node = b * BNODES + tid;
        if (node < N) {
            rowptr[node] = gbase + excl;
            dis[node] = rsqrtf(1.0f + (float)c);
        }
    }
    if (b == 0 && tid == 0) rowptr[N] = E;
    __syncthreads();

    if (cnt <= P4CAP) {
        for (int i = tid; i < cnt; i += 256) {
            unsigned v = ebuf[gbase + i];
            int pos = atomicAdd(&cursor[v >> 16], 1);
            staging[pos] = (unsigned short)(v & 0xFFFFu);
        }
        __syncthreads();
        for (int i = tid; i < cnt; i += 256)
            csr[gbase + i] = staging[i];
    } else {
        for (int i = tid; i < cnt; i += 256) {
            unsigned v = ebuf[gbase + i];
            int pos = atomicAdd(&cursor[v >> 16], 1);
            csr[gbase + pos] = (unsigned short)(v & 0xFFFFu);
        }
    }
}

// ---- xconv: Xhs = bf16(dis * X), full-occupancy streaming ----
__global__ __launch_bounds__(256) void xconv_kernel(
    const float* __restrict__ X, const float* __restrict__ dis,
    unsigned* __restrict__ Xhs, int N)
{
    int t = blockIdx.x * 256 + threadIdx.x;
    if (t >= N * (KP / 2)) return;
    int n = t / (KP / 2), c = t % (KP / 2);
    float d = dis[n];
    const float* xr = X + (size_t)n * KIN;
    float a = (2 * c     < KIN) ? d * xr[2 * c]     : 0.0f;
    float b = (2 * c + 1 < KIN) ? d * xr[2 * c + 1] : 0.0f;
    Xhs[t] = pack_bf16(a, b);
}

// ---- gather_x: one wave per node, raw sum of pre-scaled rows ----
__global__ __launch_bounds__(256) void gather_x_kernel(
    const unsigned* __restrict__ rows, const int* __restrict__ rowptr,
    const unsigned short* __restrict__ csr, unsigned* __restrict__ aggh, int N)
{
    int node = blockIdx.x * 4 + (threadIdx.x >> 6);
    if (node >= N) return;
    int lane = threadIdx.x & 63;
    bool act = lane < (KP / 2);

    float a0 = 0.0f, a1 = 0.0f;
    if (act) {
        float2 v = unpack_bf16(rows[(size_t)node * (KP / 2) + lane]);  // self
        a0 = v.x; a1 = v.y;
    }

    int beg = rowptr[node], end = rowptr[node + 1];
    int j = beg;
    for (; j + 4 <= end; j += 4) {
        int s0 = csr[j], s1 = csr[j + 1], s2 = csr[j + 2], s3 = csr[j + 3];
        if (act) {
            float2 v0 = unpack_bf16(rows[(size_t)s0 * (KP / 2) + lane]);
            float2 v1 = unpack_bf16(rows[(size_t)s1 * (KP / 2) + lane]);
            float2 v2 = unpack_bf16(rows[(size_t)s2 * (KP / 2) + lane]);
            float2 v3 = unpack_bf16(rows[(size_t)s3 * (KP / 2) + lane]);
            a0 += v0.x + v1.x + v2.x + v3.x;
            a1 += v0.y + v1.y + v2.y + v3.y;
        }
    }
    for (; j < end; ++j) {
        int sx = csr[j];
        if (act) {
            float2 v = unpack_bf16(rows[(size_t)sx * (KP / 2) + lane]);
            a0 += v.x; a1 += v.y;
        }
    }
    if (act)
        aggh[(size_t)node * (KP / 2) + lane] = pack_bf16(a0, a1);
}

// ---- gather_h: one wave per node over g2h [N][128], raw sum ----
__global__ __launch_bounds__(256) void gather_h_kernel(
    const unsigned* __restrict__ rows, const int* __restrict__ rowptr,
    const unsigned short* __restrict__ csr, unsigned* __restrict__ aggh, int N)
{
    int node = blockIdx.x * 4 + (threadIdx.x >> 6);
    if (node >= N) return;
    int lane = threadIdx.x & 63;
    int beg = rowptr[node], end = rowptr[node + 1];

    float2 sv = unpack_bf16(rows[(size_t)node * (HID / 2) + lane]);  // self
    float a0 = sv.x, a1 = sv.y;
    int j = beg;
    for (; j + 4 <= end; j += 4) {
        int s0 = csr[j], s1 = csr[j + 1], s2 = csr[j + 2], s3 = csr[j + 3];
        float2 v0 = unpack_bf16(rows[(size_t)s0 * (HID / 2) + lane]);
        float2 v1 = unpack_bf16(rows[(size_t)s1 * (HID / 2) + lane]);
        float2 v2 = unpack_bf16(rows[(size_t)s2 * (HID / 2) + lane]);
        float2 v3 = unpack_bf16(rows[(size_t)s3 * (HID / 2) + lane]);
        a0 += v0.x + v1.x + v2.x + v3.x;
        a1 += v0.y + v1.y + v2.y + v3.y;
    }
    for (; j < end; ++j) {
        int sx = csr[j];
        float2 v = unpack_bf16(rows[(size_t)sx * (HID / 2) + lane]);
        a0 += v.x; a1 += v.y;
    }
    aggh[(size_t)node * (HID / 2) + lane] = pack_bf16(a0, a1);
}

// ---- MFMA GEMM (no LDS, transposed-D epilogue) ----
// Block = 64 nodes (4 waves x 16), wave covers 128 cols as 8 16x16 tiles.
//   LAYER1: store bf16( relu(d*acc + b) * d )     (pre-scaled rows for layer 2)
//   LAYER2: store fp32( relu(d*acc + b) )
template<int KPA, bool LAYER1>
__global__ __launch_bounds__(256) void mfma_gemm_kernel(
    const unsigned short* __restrict__ A, const unsigned short* __restrict__ Wt,
    const float* __restrict__ bias, const float* __restrict__ dis,
    void* __restrict__ outp, int N)
{
    const int wave = threadIdx.x >> 6;
    const int lane = threadIdx.x & 63;
    const int m    = lane & 15;
    const int quad = lane >> 4;
    const int row0 = blockIdx.x * 64 + wave * 16;
    const int node = row0 + m;

    f32x4 acc[8];
#pragma unroll
    for (int t = 0; t < 8; ++t) acc[t] = (f32x4){0.0f, 0.0f, 0.0f, 0.0f};

    const int arow = min(node, N - 1);           // clamp: stores are guarded
    const unsigned short* arp = A + (size_t)arow * KPA;

#pragma unroll
    for (int c = 0; c < KPA / 32; ++c) {
        const int k0 = c * 32 + quad * 8;
        bf16x8 nv = *(const bf16x8*)(arp + k0);                      // B-frag
#pragma unroll
        for (int t = 0; t < 8; ++t) {
            bf16x8 wv = *(const bf16x8*)(Wt + (size_t)(t * 16 + m) * KPA + k0);  // A-frag
            acc[t] = __builtin_amdgcn_mfma_f32_16x16x32_bf16(wv, nv, acc[t], 0, 0, 0);
        }
    }

    if (node < N) {
        const float dv = dis[node];
#pragma unroll
        for (int t = 0; t < 8; ++t) {
            const int col0 = t * 16 + quad * 4;
            float4 bb = *(const float4*)&bias[col0];
            float r0 = fmaxf(fmaf(dv, acc[t][0], bb.x), 0.0f);
            float r1 = fmaxf(fmaf(dv, acc[t][1], bb.y), 0.0f);
            float r2 = fmaxf(fmaf(dv, acc[t][2], bb.z), 0.0f);
            float r3 = fmaxf(fmaf(dv, acc[t][3], bb.w), 0.0f);
            if (LAYER1) {
                uint2 u;
                u.x = pack_bf16(r0 * dv, r1 * dv);
                u.y = pack_bf16(r2 * dv, r3 * dv);
                *(uint2*)((unsigned short*)outp + (size_t)node * HID + col0) = u;
            } else {
                float4 r = make_float4(r0, r1, r2, r3);
                *(float4*)((float*)outp + (size_t)node * HID + col0) = r;
            }
        }
    }
}

// ---------------- launch ----------------

static inline char* wsal(char*& p, size_t n) {
    uintptr_t q = ((uintptr_t)p + 255) & ~(uintptr_t)255;
    char* r = (char*)q;
    p = r + n;
    return r;
}

extern "C" void kernel_launch(void* const* d_in, const int* in_sizes, int n_in,
                              void* d_out, int out_size, void* d_ws, size_t ws_size,
                              hipStream_t stream) {
    const float* x  = (const float*)d_in[0];
    const int*   ei = (const int*)d_in[1];
    const float* W1 = (const float*)d_in[2];
    const float* b1 = (const float*)d_in[3];
    const float* W2 = (const float*)d_in[4];
    const float* b2 = (const float*)d_in[5];

    const int N = in_sizes[0] / KIN;  // 50000  (< 65536 required)
    const int E = in_sizes[1] / 2;    // 800000
    const int nbuck = (N + BNODES - 1) >> BSH;   // 391 (<= MAXBUCK)

    float* out  = (float*)d_out;
    float* outH = out;                      // [N,128] final fp32 output
    float* outE = out + (size_t)N * HID;    // [2,E] edge_index as float

    char* ws = (char*)d_ws;
    int*            histG  = (int*)wsal(ws, (size_t)MAXBUCK * NPB * 4);
    int*            totals = (int*)wsal(ws, MAXBUCK * 4);
    int*            rowptr = (int*)wsal(ws, (size_t)(N + 1) * 4);
    float*          dis    = (float*)wsal(ws, (size_t)N * 4);
    unsigned*       ebuf   = (unsigned*)wsal(ws, (size_t)E * 4);
    unsigned short* csr    = (unsigned short*)wsal(ws, (size_t)E * 2);
    unsigned*       Xhs    = (unsigned*)wsal(ws, (size_t)N * (KP / 2) * 4);
    unsigned*       agg1h  = (unsigned*)wsal(ws, (size_t)N * (KP / 2) * 4);
    unsigned short* g2h    = (unsigned short*)wsal(ws, (size_t)N * HID * 2);
    unsigned short* agg2h  = (unsigned short*)wsal(ws, (size_t)N * HID * 2);
    unsigned short* W1t    = (unsigned short*)wsal(ws, (size_t)HID * KP * 2);
    unsigned short* W2t    = (unsigned short*)wsal(ws, (size_t)HID * HID * 2);

    p1_kernel<<<NPB, 256, 0, stream>>>(ei, outE, histG, W1, W1t, W2, W2t, E, nbuck);
    p2a_kernel<<<nbuck, NPB, 0, stream>>>(histG, totals);
    p3_part_kernel<<<NPB, 256, 0, stream>>>(ei, histG, totals, ebuf, E, nbuck);
    p4_sort_kernel<<<nbuck, 256, 0, stream>>>(ebuf, totals, csr, rowptr, dis,
                                              N, E, nbuck);
    xconv_kernel<<<(N * (KP / 2) + 255) / 256, 256, 0, stream>>>(x, dis, Xhs, N);

    const int ngt = (N + 3) / 4;
    const int ngm = (N + 63) / 64;

    // Layer 1
    gather_x_kernel<<<ngt, 256, 0, stream>>>(Xhs, rowptr, csr, agg1h, N);
    mfma_gemm_kernel<KP, true><<<ngm, 256, 0, stream>>>(
        (const unsigned short*)agg1h, W1t, b1, dis, g2h, N);

    // Layer 2
    gather_h_kernel<<<ngt, 256, 0, stream>>>((const unsigned*)g2h, rowptr, csr,
                                             (unsigned*)agg2h, N);
    mfma_gemm_kernel<HID, false><<<ngm, 256, 0, stream>>>(
        agg2h, W2t, b2, dis, outH, N);
}